// Round 2
// baseline (1160.864 us; speedup 1.0000x reference)
//
#include <hip/hip_runtime.h>
#include <float.h>

#define NROWS 65536
#define DK 256
#define NCODES 1024
#define FLAG_CAP 16384
#define FLAG2_CAP 512
#define MARGIN1 1.0f     // bf16-phase margin: true margin >= 0.75 after 0.25 quantization granule; err sigma ~0.09
#define MARGIN2 1e-2f    // fp32-phase margin: exact-fp32 dot err ~2e-5

#define LOSS_OFF 16777216
#define IDX_OFF  16777217

// ---------------- ws layout (bytes) ----------------
#define WS_FLAG1   0        // int
#define WS_FLAG2   4        // int
#define WS_LOSSP   8        // double[64]
#define WS_ENORMD  520      // double[1024]
#define WS_ENORMF  8712     // float[1024]
#define WS_FROWS   12808    // int[FLAG_CAP]
#define WS_F2ROWS  78344    // int[FLAG2_CAP]
#define WS_IDX     80392    // int[65536]
#define WS_EFRAG   342544   // ushort[1024*256] bf16, MFMA-fragment-swizzled; total ~867 KB

typedef __bf16 bf16x8 __attribute__((ext_vector_type(8)));
typedef float f32x4 __attribute__((ext_vector_type(4)));
typedef unsigned int uint32;
typedef unsigned short ushort16;

__device__ __forceinline__ uint32 bf16rne(float f) {
  uint32 u = __builtin_bit_cast(uint32, f);
  return (u + 0x7fffu + ((u >> 16) & 1u)) >> 16;
}
__device__ __forceinline__ uint32 pack2(float a, float b) {
  return bf16rne(a) | (bf16rne(b) << 16);
}

// ---- init: zero counters, E norms (fp64), E -> bf16 fragment-swizzled E_frag ----
__global__ __launch_bounds__(256) void init_kernel(
    const float* __restrict__ E, double* __restrict__ enorm_d,
    float* __restrict__ enorm_f, ushort16* __restrict__ Efrag,
    int* __restrict__ flag1, int* __restrict__ flag2,
    double* __restrict__ loss_part) {
  const int c = blockIdx.x * 256 + threadIdx.x;  // one code per thread
  if (blockIdx.x == 0) {
    if (threadIdx.x == 0) *flag1 = 0;
    if (threadIdx.x == 1) *flag2 = 0;
    if (threadIdx.x < 64) loss_part[threadIdx.x] = 0.0;
  }
  const float* er = E + (size_t)c * DK;
  double s = 0.0;
  for (int k = 0; k < DK; ++k) { const double v = er[k]; s += v * v; }
  enorm_d[c] = s;
  enorm_f[c] = (float)s;
  // swizzle: unit u = ((ctg*4+kc)*32 + cga*2+ks), lane = quad*16+col, 16B per (u,lane)
  const int ctg = c >> 8, cga = (c >> 4) & 15, col = c & 15;
  for (int k8 = 0; k8 < 32; ++k8) {
    const int k = k8 * 8;
    const int kc = k >> 6, ks = (k >> 5) & 1, quad = (k >> 3) & 3;
    uint4 v;
    v.x = pack2(er[k + 0], er[k + 1]);
    v.y = pack2(er[k + 2], er[k + 3]);
    v.z = pack2(er[k + 4], er[k + 5]);
    v.w = pack2(er[k + 6], er[k + 7]);
    const size_t u = (((size_t)(ctg * 4 + kc) * 32) + (size_t)(cga * 2 + ks)) * 64
                     + (size_t)(quad * 16 + col);
    ((uint4*)Efrag)[u] = v;
  }
}

// ---- phase 1: bf16 MFMA distance GEMM + packed top-2 argmin ----
// block = 256 thr (4 waves), 64 rows x all 1024 codes. LDS: A 32KB (resident,
// frag order) + B 32KB (per 64-k chunk via global_load_lds w=16). Wave w owns
// codes w*64..+63 of each 256-code group; 4x4 grid of 16x16x32 MFMAs/wave.
__global__ __launch_bounds__(256, 2) void dist_argmin_mfma(
    const float* __restrict__ X, const ushort16* __restrict__ Efrag,
    const float* __restrict__ enorm_f, int* __restrict__ idx_ws,
    int* __restrict__ flag1, int* __restrict__ flag_rows) {
  __shared__ __attribute__((aligned(16))) char lds[65536];
  const int tid = threadIdx.x;
  const int lane = tid & 63;
  const int wid = tid >> 6;
  const int col = lane & 15;
  const int rowBase = blockIdx.x * 64;

  // stage A: 64 rows x 256 k fp32 -> bf16 RNE, fragment order. Once per block.
  {
    const float4* X4 = (const float4*)X + (size_t)rowBase * 64;
    #pragma unroll
    for (int i = 0; i < 16; ++i) {
      const int f4 = i * 256 + tid;
      const int row = f4 >> 6;
      const int k0 = (f4 & 63) << 2;
      const float4 v = X4[f4];
      uint2 p;
      p.x = pack2(v.x, v.y);
      p.y = pack2(v.z, v.w);
      const int off = (((row >> 4) * 8 + (k0 >> 5)) * 64 + ((k0 >> 3) & 3) * 16 + (row & 15)) * 16
                      + ((k0 >> 2) & 1) * 8;
      *(uint2*)(lds + off) = p;
    }
  }

  float rv1[16], rv2[16];  // running packed top-2 per (rg,reg) row; idx in low 10 bits
  #pragma unroll
  for (int i = 0; i < 16; ++i) { rv1[i] = FLT_MAX; rv2[i] = FLT_MAX; }

  for (int ctg = 0; ctg < 4; ++ctg) {
    f32x4 acc[4][4];
    #pragma unroll
    for (int rg = 0; rg < 4; ++rg)
      #pragma unroll
      for (int cg = 0; cg < 4; ++cg) acc[rg][cg] = (f32x4){0.f, 0.f, 0.f, 0.f};

    for (int kc = 0; kc < 4; ++kc) {
      __syncthreads();  // A visible (1st iter) / previous chunk's B reads done
      {
        const char* gbase = (const char*)Efrag + ((size_t)(ctg * 4 + kc) * 32) * 1024;
        #pragma unroll
        for (int s2 = 0; s2 < 8; ++s2) {
          const int u = wid * 8 + s2;
          __builtin_amdgcn_global_load_lds(
              (const __attribute__((address_space(1))) uint32*)(gbase + (size_t)u * 1024 + (size_t)lane * 16),
              (__attribute__((address_space(3))) uint32*)(lds + 32768 + u * 1024),
              16, 0, 0);
        }
      }
      __syncthreads();  // B staged (barrier drains vmcnt)
      #pragma unroll
      for (int ks = 0; ks < 2; ++ks) {
        const int kstep = kc * 2 + ks;
        bf16x8 a[4], b[4];
        #pragma unroll
        for (int rg = 0; rg < 4; ++rg)
          a[rg] = *(const bf16x8*)(lds + ((rg * 8 + kstep) * 64 + lane) * 16);
        #pragma unroll
        for (int cg = 0; cg < 4; ++cg)
          b[cg] = *(const bf16x8*)(lds + 32768 + (((wid * 4 + cg) * 2 + ks) * 64 + lane) * 16);
        #pragma unroll
        for (int rg = 0; rg < 4; ++rg)
          #pragma unroll
          for (int cg = 0; cg < 4; ++cg)
            acc[rg][cg] = __builtin_amdgcn_mfma_f32_16x16x32_bf16(a[rg], b[cg], acc[rg][cg], 0, 0, 0);
      }
    }
    // epilogue: d' = enorm+1024-2*acc > 0 always; pack code into low 10 mantissa bits
    float en[4]; uint32 cbase[4];
    #pragma unroll
    for (int cg = 0; cg < 4; ++cg) {
      cbase[cg] = (uint32)(ctg * 256 + wid * 64 + cg * 16 + col);
      en[cg] = enorm_f[cbase[cg]] + 1024.0f;
    }
    #pragma unroll
    for (int rg = 0; rg < 4; ++rg)
      #pragma unroll
      for (int reg = 0; reg < 4; ++reg) {
        const int i = rg * 4 + reg;
        #pragma unroll
        for (int cg = 0; cg < 4; ++cg) {
          const float d = fmaf(-2.0f, acc[rg][cg][reg], en[cg]);
          const float p = __builtin_bit_cast(float,
              (__builtin_bit_cast(uint32, d) & 0xFFFFFC00u) | cbase[cg]);
          rv2[i] = fminf(rv2[i], fmaxf(rv1[i], p));
          rv1[i] = fminf(rv1[i], p);
        }
      }
  }

  // merge the 16 cols within each quad (butterfly; packed => lowest idx wins ties)
  #pragma unroll
  for (int i = 0; i < 16; ++i) {
    #pragma unroll
    for (int m = 1; m < 16; m <<= 1) {
      const float o1 = __shfl_xor(rv1[i], m, 64);
      const float o2 = __shfl_xor(rv2[i], m, 64);
      rv2[i] = fminf(fminf(rv2[i], o2), fmaxf(rv1[i], o1));
      rv1[i] = fminf(rv1[i], o1);
    }
  }

  __syncthreads();  // all waves done with B area
  float* M = (float*)(lds + 32768);  // [row 64][wave 4][2]
  if (col == 0) {
    const int quad = lane >> 4;
    #pragma unroll
    for (int i = 0; i < 16; ++i) {
      const int row = (i >> 2) * 16 + quad * 4 + (i & 3);
      M[(row * 4 + wid) * 2 + 0] = rv1[i];
      M[(row * 4 + wid) * 2 + 1] = rv2[i];
    }
  }
  __syncthreads();
  if (tid < 64) {
    const float a1 = M[(tid * 4 + 0) * 2], a2 = M[(tid * 4 + 0) * 2 + 1];
    const float b1 = M[(tid * 4 + 1) * 2], b2 = M[(tid * 4 + 1) * 2 + 1];
    const float c1 = M[(tid * 4 + 2) * 2], c2 = M[(tid * 4 + 2) * 2 + 1];
    const float d1 = M[(tid * 4 + 3) * 2], d2 = M[(tid * 4 + 3) * 2 + 1];
    const float lo1 = fminf(a1, b1), hi1 = fmaxf(a1, b1);
    const float lo2 = fminf(c1, d1), hi2 = fmaxf(c1, d1);
    const float r1 = fminf(lo1, lo2);
    const float s1 = fminf(fmaxf(lo1, lo2), fminf(hi1, hi2));  // 2nd-min of the four mins
    const float r2 = fminf(fminf(fminf(a2, b2), fminf(c2, d2)), s1);
    const uint32 u1 = __builtin_bit_cast(uint32, r1);
    const int row = rowBase + tid;
    idx_ws[row] = (int)(u1 & 1023u);
    const float q1 = __builtin_bit_cast(float, u1 & 0xFFFFFC00u);
    const float q2 = __builtin_bit_cast(float, __builtin_bit_cast(uint32, r2) & 0xFFFFFC00u);
    if (q2 - q1 < MARGIN1) {
      const int p = atomicAdd(flag1, 1);
      if (p < FLAG_CAP) flag_rows[p] = row;
    }
  }
}

// ---- phase 2: exact-fp32 re-resolution of flagged rows (16 rows/block) ----
__global__ __launch_bounds__(256) void fixup32(
    const float* __restrict__ X, const float* __restrict__ E,
    const float* __restrict__ enorm_f, const int* __restrict__ flag1,
    const int* __restrict__ flag_rows, int* __restrict__ idx_ws,
    int* __restrict__ flag2, int* __restrict__ flag2_rows) {
  __shared__ float xs[16][260];  // +4 pad: kills row-stride bank conflicts
  int cnt = *flag1;
  if (cnt > FLAG_CAP) cnt = FLAG_CAP;
  const int nb = (cnt + 15) >> 4;
  for (int g = blockIdx.x; g < nb; g += gridDim.x) {
    const int rbase = g * 16;
    const int nr = min(16, cnt - rbase);
    __syncthreads();
    for (int e = threadIdx.x; e < 16 * 256; e += 256) {
      const int r = e >> 8, k = e & 255;
      if (r < nr) xs[r][k] = X[(size_t)flag_rows[rbase + r] * DK + k];
    }
    __syncthreads();
    const int r = threadIdx.x >> 4, c0 = threadIdx.x & 15;
    float v1 = FLT_MAX, v2 = FLT_MAX;
    int i1 = 0x7fffffff;
    if (r < nr) {
      const float4* x4 = (const float4*)&xs[r][0];
      for (int c = c0; c < NCODES; c += 16) {
        const float4* E4 = (const float4*)E + (size_t)c * 64;
        float s0 = 0.f, s1 = 0.f, s2 = 0.f, s3 = 0.f;
        #pragma unroll 8
        for (int q = 0; q < 64; ++q) {
          const float4 ev = E4[q];
          const float4 xv = x4[q];
          s0 = fmaf(xv.x, ev.x, s0);
          s1 = fmaf(xv.y, ev.y, s1);
          s2 = fmaf(xv.z, ev.z, s2);
          s3 = fmaf(xv.w, ev.w, s3);
        }
        const float d = enorm_f[c] - 2.0f * ((s0 + s1) + (s2 + s3));
        if (d < v1) { v2 = v1; v1 = d; i1 = c; }
        else if (d < v2) v2 = d;
      }
    }
    #pragma unroll
    for (int m = 1; m < 16; m <<= 1) {  // merge 16 lanes of a row group
      const float o1 = __shfl_xor(v1, m, 64);
      const float o2 = __shfl_xor(v2, m, 64);
      const int   oi = __shfl_xor(i1, m, 64);
      const bool take = (o1 < v1) || (o1 == v1 && oi < i1);
      const float n2 = fminf(fminf(v2, o2), take ? v1 : o1);
      v1 = take ? o1 : v1;
      i1 = take ? oi : i1;
      v2 = n2;
    }
    if (r < nr && c0 == 0) {
      const int grow = flag_rows[rbase + r];
      idx_ws[grow] = i1;
      if (v2 - v1 < MARGIN2) {
        const int p = atomicAdd(flag2, 1);
        if (p < FLAG2_CAP) flag2_rows[p] = grow;
      }
    }
  }
}

// ---- phase 3: exact fp64 for near-ties (expected ~40 rows) ----
__global__ __launch_bounds__(256) void fixup64(
    const float* __restrict__ X, const float* __restrict__ E,
    const double* __restrict__ enorm_d, const int* __restrict__ flag2,
    const int* __restrict__ flag2_rows, int* __restrict__ idx_ws) {
  __shared__ float xsb[DK];
  __shared__ double rv[256];
  __shared__ int ri[256];
  int cnt = *flag2;
  if (cnt > FLAG2_CAP) cnt = FLAG2_CAP;
  for (int f = blockIdx.x; f < cnt; f += gridDim.x) {
    const int row = flag2_rows[f];
    __syncthreads();
    xsb[threadIdx.x] = X[(size_t)row * DK + threadIdx.x];
    __syncthreads();
    double bestv = 1.0e300;
    int besti = 0x7fffffff;
    for (int c = threadIdx.x; c < NCODES; c += 256) {
      double s = 0.0;
      for (int k = 0; k < DK; ++k)
        s += (double)xsb[k] * (double)E[(size_t)c * DK + k];
      const double d = enorm_d[c] - 2.0 * s;
      if (d < bestv || (d == bestv && c < besti)) { bestv = d; besti = c; }
    }
    rv[threadIdx.x] = bestv;
    ri[threadIdx.x] = besti;
    __syncthreads();
    for (int off = 128; off > 0; off >>= 1) {
      if (threadIdx.x < off) {
        const double ov = rv[threadIdx.x + off];
        const int oi = ri[threadIdx.x + off];
        if (ov < rv[threadIdx.x] || (ov == rv[threadIdx.x] && oi < ri[threadIdx.x])) {
          rv[threadIdx.x] = ov;
          ri[threadIdx.x] = oi;
        }
      }
      __syncthreads();
    }
    if (threadIdx.x == 0) idx_ws[row] = ri[0];
  }
}

// ---- phase 4: gather + indices + fp64 loss (float4 vectorized) ----
__global__ __launch_bounds__(256) void gather_loss(
    const float* __restrict__ X, const float* __restrict__ E,
    const int* __restrict__ idx_ws, float* __restrict__ out,
    double* __restrict__ loss_part) {
  const int t = threadIdx.x;
  const int rsub = t >> 6, c4 = t & 63;
  const int rowBase = blockIdx.x * 16;
  double ls = 0.0;
  #pragma unroll
  for (int i = 0; i < 4; ++i) {
    const int row = rowBase + i * 4 + rsub;
    const int idx = idx_ws[row];
    const float4 q = ((const float4*)E)[(size_t)idx * 64 + c4];
    const float4 x = ((const float4*)X)[(size_t)row * 64 + c4];
    ((float4*)out)[(size_t)row * 64 + c4] = q;  // quantized_st == quantized numerically
    const double d0 = (double)q.x - (double)x.x;
    const double d1 = (double)q.y - (double)x.y;
    const double d2 = (double)q.z - (double)x.z;
    const double d3 = (double)q.w - (double)x.w;
    ls += d0 * d0 + d1 * d1 + d2 * d2 + d3 * d3;
    if (c4 == 0) out[IDX_OFF + row] = (float)idx;
  }
  for (int o = 32; o > 0; o >>= 1) ls += __shfl_down(ls, o, 64);
  __shared__ double wsum[4];
  if ((t & 63) == 0) wsum[t >> 6] = ls;
  __syncthreads();
  if (t == 0)
    atomicAdd(&loss_part[blockIdx.x & 63], wsum[0] + wsum[1] + wsum[2] + wsum[3]);
}

__global__ __launch_bounds__(64) void finalize(
    const double* __restrict__ loss_part, float* __restrict__ out) {
  double v = loss_part[threadIdx.x];
  for (int o = 32; o > 0; o >>= 1) v += __shfl_down(v, o, 64);
  if (threadIdx.x == 0) out[LOSS_OFF] = (float)(v / 16777216.0);
}

extern "C" void kernel_launch(void* const* d_in, const int* in_sizes, int n_in,
                              void* d_out, int out_size, void* d_ws, size_t ws_size,
                              hipStream_t stream) {
  const float* X = (const float*)d_in[0];  // [65536, 256]
  const float* E = (const float*)d_in[1];  // [1024, 256]
  float* out = (float*)d_out;
  char* ws = (char*)d_ws;

  int*      flag1      = (int*)(ws + WS_FLAG1);
  int*      flag2      = (int*)(ws + WS_FLAG2);
  double*   loss_part  = (double*)(ws + WS_LOSSP);
  double*   enorm_d    = (double*)(ws + WS_ENORMD);
  float*    enorm_f    = (float*)(ws + WS_ENORMF);
  int*      flag_rows  = (int*)(ws + WS_FROWS);
  int*      flag2_rows = (int*)(ws + WS_F2ROWS);
  int*      idx_ws     = (int*)(ws + WS_IDX);
  ushort16* Efrag      = (ushort16*)(ws + WS_EFRAG);

  hipLaunchKernelGGL(init_kernel, dim3(4), dim3(256), 0, stream,
                     E, enorm_d, enorm_f, Efrag, flag1, flag2, loss_part);
  hipLaunchKernelGGL(dist_argmin_mfma, dim3(NROWS / 64), dim3(256), 0, stream,
                     X, Efrag, enorm_f, idx_ws, flag1, flag_rows);
  hipLaunchKernelGGL(fixup32, dim3(512), dim3(256), 0, stream,
                     X, E, enorm_f, flag1, flag_rows, idx_ws, flag2, flag2_rows);
  hipLaunchKernelGGL(fixup64, dim3(64), dim3(256), 0, stream,
                     X, E, enorm_d, flag2, flag2_rows, idx_ws);
  hipLaunchKernelGGL(gather_loss, dim3(NROWS / 16), dim3(256), 0, stream,
                     X, E, idx_ws, out, loss_part);
  hipLaunchKernelGGL(finalize, dim3(1), dim3(64), 0, stream, loss_part, out);
}

// Round 3
// 259.475 us; speedup vs baseline: 4.4739x; 4.4739x over previous
//
#include <hip/hip_runtime.h>
#include <float.h>

#define NROWS 65536
#define DK 256
#define NCODES 1024
#define FLAG_CAP 8192
#define MARGIN1 0.10f   // 2E(12sigma=0.054) + granule(0.0156) + pad
#define D_BIAS 384.0f   // keeps packed d in (0, 1024): granule <= 2^-6 with 8 idx bits

#define LOSS_OFF 16777216
#define IDX_OFF  16777217

// ---------------- ws layout (bytes) ----------------
#define WS_FLAG1   0        // int
#define WS_LOSSP   8        // double[64]
#define WS_ENORMD  520      // double[1024]
#define WS_ENORMF  8712     // float[1024]
#define WS_FROWS   12808    // int[FLAG_CAP] -> ends 45576
#define WS_IDX     45576    // int[65536]    -> ends 307720
#define WS_EHI     307728   // fp16[1024*256] frag-swizzled (512 KB)
#define WS_ELO     832016   // fp16[1024*256] frag-swizzled (512 KB); total ~1.36 MB

typedef _Float16 f16x8 __attribute__((ext_vector_type(8)));
typedef float f32x4 __attribute__((ext_vector_type(4)));
typedef unsigned int uint32;

__device__ __forceinline__ uint32 packh2(float a, float b) {
  return (uint32)__builtin_bit_cast(unsigned short, (_Float16)a) |
         ((uint32)__builtin_bit_cast(unsigned short, (_Float16)b) << 16);
}
__device__ __forceinline__ void splitpack2(float a, float b, uint32& hi, uint32& lo) {
  const _Float16 ah = (_Float16)a, bh = (_Float16)b;
  const _Float16 al = (_Float16)(a - (float)ah);
  const _Float16 bl = (_Float16)(b - (float)bh);
  hi = (uint32)__builtin_bit_cast(unsigned short, ah) |
       ((uint32)__builtin_bit_cast(unsigned short, bh) << 16);
  lo = (uint32)__builtin_bit_cast(unsigned short, al) |
       ((uint32)__builtin_bit_cast(unsigned short, bl) << 16);
}

// ---- init: counters, fp64 E norms, E -> (hi, lo) fp16 fragment-swizzled ----
__global__ __launch_bounds__(256) void init_kernel(
    const float* __restrict__ E, double* __restrict__ enorm_d,
    float* __restrict__ enorm_f, uint4* __restrict__ Ehi, uint4* __restrict__ Elo,
    int* __restrict__ flag1, double* __restrict__ loss_part) {
  const int c = blockIdx.x * 256 + threadIdx.x;  // one code per thread
  if (blockIdx.x == 0) {
    if (threadIdx.x == 0) *flag1 = 0;
    if (threadIdx.x < 64) loss_part[threadIdx.x] = 0.0;
  }
  const float4* er4 = (const float4*)(E + (size_t)c * DK);
  const int ctg = c >> 8, cga = (c >> 4) & 15, col = c & 15;
  double s = 0.0;
  for (int g = 0; g < 32; ++g) {  // 8 elements / iter
    const float4 va = er4[g * 2];
    const float4 vb = er4[g * 2 + 1];
    s += (double)va.x * va.x + (double)va.y * va.y + (double)va.z * va.z + (double)va.w * va.w;
    s += (double)vb.x * vb.x + (double)vb.y * vb.y + (double)vb.z * vb.z + (double)vb.w * vb.w;
    uint4 h, l;
    splitpack2(va.x, va.y, h.x, l.x);
    splitpack2(va.z, va.w, h.y, l.y);
    splitpack2(vb.x, vb.y, h.z, l.z);
    splitpack2(vb.z, vb.w, h.w, l.w);
    const int kc = g >> 2, quad = g & 3;
    const size_t u = ((size_t)((ctg * 8 + kc) * 16 + cga)) * 64 + (size_t)(quad * 16 + col);
    Ehi[u] = h;
    Elo[u] = l;
  }
  enorm_d[c] = s;
  enorm_f[c] = (float)s;
}

// ---- phase 1: fp16 2-term MFMA distances + packed top-2 argmin ----
// 256 thr / 4 waves, 64 rows x all 1024 codes. A (x_hi) resident in 32 KB LDS,
// frag order; B fragments loaded global->VGPR (coalesced, zero reuse => no LDS
// hop, no K-loop barriers). Wave w owns codes w*64..+63 of each 256-code group.
__global__ __launch_bounds__(256, 2) void dist_argmin_mfma(
    const float* __restrict__ X, const uint4* __restrict__ Ehi,
    const uint4* __restrict__ Elo, const float* __restrict__ enorm_f,
    int* __restrict__ idx_ws, int* __restrict__ flag1, int* __restrict__ flag_rows) {
  __shared__ __attribute__((aligned(16))) char lds[32768];
  const int tid = threadIdx.x;
  const int lane = tid & 63;
  const int wid = tid >> 6;
  const int col = lane & 15;
  const int rowBase = blockIdx.x * 64;

  // stage A: 64 rows x 256 k, fp32 -> fp16 RNE, fragment order
  {
    const float4* X4 = (const float4*)X + (size_t)rowBase * 64;
    #pragma unroll
    for (int i = 0; i < 16; ++i) {
      const int f4 = i * 256 + tid;
      const int row = f4 >> 6;
      const int k0 = (f4 & 63) << 2;
      const float4 v = X4[f4];
      uint2 p;
      p.x = packh2(v.x, v.y);
      p.y = packh2(v.z, v.w);
      const int off = (((row >> 4) * 8 + (k0 >> 5)) * 64 + ((k0 >> 3) & 3) * 16 + (row & 15)) * 16
                      + ((k0 >> 2) & 1) * 8;
      *(uint2*)(lds + off) = p;
    }
  }
  __syncthreads();

  float rv1[16], rv2[16];  // packed top-2 per row; wave-local idx in low 8 bits
  #pragma unroll
  for (int i = 0; i < 16; ++i) { rv1[i] = FLT_MAX; rv2[i] = FLT_MAX; }

  for (int ctg = 0; ctg < 4; ++ctg) {
    f32x4 acc[4][4];
    #pragma unroll
    for (int rg = 0; rg < 4; ++rg)
      #pragma unroll
      for (int cg = 0; cg < 4; ++cg) acc[rg][cg] = (f32x4){0.f, 0.f, 0.f, 0.f};

    #pragma unroll 2
    for (int ks = 0; ks < 8; ++ks) {
      const size_t ub = ((size_t)((ctg * 8 + ks) * 16 + wid * 4)) * 64 + (size_t)lane;
      f16x8 a[4], bh[4], bl[4];
      #pragma unroll
      for (int cg = 0; cg < 4; ++cg) bh[cg] = *(const f16x8*)&Ehi[ub + (size_t)cg * 64];
      #pragma unroll
      for (int cg = 0; cg < 4; ++cg) bl[cg] = *(const f16x8*)&Elo[ub + (size_t)cg * 64];
      #pragma unroll
      for (int rg = 0; rg < 4; ++rg)
        a[rg] = *(const f16x8*)(lds + ((rg * 8 + ks) * 64 + lane) * 16);
      #pragma unroll
      for (int rg = 0; rg < 4; ++rg)
        #pragma unroll
        for (int cg = 0; cg < 4; ++cg) {
          acc[rg][cg] = __builtin_amdgcn_mfma_f32_16x16x32_f16(a[rg], bh[cg], acc[rg][cg], 0, 0, 0);
          acc[rg][cg] = __builtin_amdgcn_mfma_f32_16x16x32_f16(a[rg], bl[cg], acc[rg][cg], 0, 0, 0);
        }
    }
    // epilogue: d = ||e||^2 + BIAS - 2 acc in (0,1024); pack local idx (8 bits)
    #pragma unroll
    for (int cg = 0; cg < 4; ++cg) {
      const int code = ctg * 256 + wid * 64 + cg * 16 + col;
      const float en = enorm_f[code] + D_BIAS;
      const uint32 li = (uint32)((ctg << 6) | (cg << 4) | col);
      #pragma unroll
      for (int rg = 0; rg < 4; ++rg)
        #pragma unroll
        for (int reg = 0; reg < 4; ++reg) {
          const int i = rg * 4 + reg;
          const float d = fmaf(-2.0f, acc[rg][cg][reg], en);
          const float p = __builtin_bit_cast(float,
              (__builtin_bit_cast(uint32, d) & 0xFFFFFF00u) | li);
          rv2[i] = fminf(rv2[i], fmaxf(rv1[i], p));
          rv1[i] = fminf(rv1[i], p);
        }
    }
  }

  // merge 16 cols within each quad (packed => lowest local idx wins ties)
  #pragma unroll
  for (int i = 0; i < 16; ++i) {
    #pragma unroll
    for (int m = 1; m < 16; m <<= 1) {
      const float o1 = __shfl_xor(rv1[i], m, 64);
      const float o2 = __shfl_xor(rv2[i], m, 64);
      rv2[i] = fminf(fminf(rv2[i], o2), fmaxf(rv1[i], o1));
      rv1[i] = fminf(rv1[i], o1);
    }
  }

  __syncthreads();  // all waves done reading A region
  float* M = (float*)lds;  // [row 64][wave 4][2]
  if (col == 0) {
    const int quad = lane >> 4;
    #pragma unroll
    for (int i = 0; i < 16; ++i) {
      const int row = (i >> 2) * 16 + quad * 4 + (i & 3);
      M[(row * 4 + wid) * 2 + 0] = rv1[i];
      M[(row * 4 + wid) * 2 + 1] = rv2[i];
    }
  }
  __syncthreads();
  if (tid < 64) {
    const float a1 = M[(tid * 4 + 0) * 2], a2 = M[(tid * 4 + 0) * 2 + 1];
    const float b1 = M[(tid * 4 + 1) * 2], b2 = M[(tid * 4 + 1) * 2 + 1];
    const float c1 = M[(tid * 4 + 2) * 2], c2 = M[(tid * 4 + 2) * 2 + 1];
    const float d1 = M[(tid * 4 + 3) * 2], d2 = M[(tid * 4 + 3) * 2 + 1];
    const float lo1 = fminf(a1, b1), hi1 = fmaxf(a1, b1);
    const float lo2 = fminf(c1, d1), hi2 = fmaxf(c1, d1);
    const float r1 = fminf(lo1, lo2);
    const float s1 = fminf(fmaxf(lo1, lo2), fminf(hi1, hi2));
    const float r2 = fminf(fminf(fminf(a2, b2), fminf(c2, d2)), s1);
    const int w1 = (r1 == a1) ? 0 : (r1 == b1) ? 1 : (r1 == c1) ? 2 : 3;  // lowest wid on tie
    const uint32 u1 = __builtin_bit_cast(uint32, r1);
    const int li = (int)(u1 & 255u);
    const int code = ((li >> 6) & 3) * 256 + w1 * 64 + ((li >> 4) & 3) * 16 + (li & 15);
    const int row = rowBase + tid;
    idx_ws[row] = code;
    const float q1 = __builtin_bit_cast(float, u1 & 0xFFFFFF00u);
    const float q2 = __builtin_bit_cast(float, __builtin_bit_cast(uint32, r2) & 0xFFFFFF00u);
    if (q2 - q1 < MARGIN1) {
      const int p = atomicAdd(flag1, 1);
      if (p < FLAG_CAP) flag_rows[p] = row;
    }
  }
}

// ---- phase 2: exact fp64 re-resolution, 4 flagged rows per block ----
__global__ __launch_bounds__(256) void fixup64(
    const float* __restrict__ X, const float* __restrict__ E,
    const double* __restrict__ enorm_d, const int* __restrict__ flag1,
    const int* __restrict__ flag_rows, int* __restrict__ idx_ws) {
  __shared__ float xs[4][256];
  __shared__ double rv[256];
  __shared__ int ri[256];
  int cnt = *flag1;
  if (cnt > FLAG_CAP) cnt = FLAG_CAP;
  const int fbase = blockIdx.x * 4;
  if (fbase >= cnt) return;
  const int nr = min(4, cnt - fbase);
  for (int e = threadIdx.x; e < nr * 256; e += 256) {
    const int r = e >> 8, k = e & 255;
    xs[r][k] = X[(size_t)flag_rows[fbase + r] * DK + k];
  }
  __syncthreads();
  double best[4] = {1e300, 1e300, 1e300, 1e300};
  int bi[4] = {0x7fffffff, 0x7fffffff, 0x7fffffff, 0x7fffffff};
  for (int cc = 0; cc < 4; ++cc) {
    const int c = cc * 256 + threadIdx.x;  // ascending per thread => strict '<' keeps lowest
    const float4* E4 = (const float4*)(E + (size_t)c * DK);
    double s0 = 0.0, s1 = 0.0, s2 = 0.0, s3 = 0.0;
    #pragma unroll 4
    for (int q = 0; q < 64; ++q) {
      const float4 ev = E4[q];
      const float4 x0 = ((const float4*)xs[0])[q];
      const float4 x1 = ((const float4*)xs[1])[q];
      const float4 x2 = ((const float4*)xs[2])[q];
      const float4 x3 = ((const float4*)xs[3])[q];
      s0 += (double)ev.x * x0.x + (double)ev.y * x0.y + (double)ev.z * x0.z + (double)ev.w * x0.w;
      s1 += (double)ev.x * x1.x + (double)ev.y * x1.y + (double)ev.z * x1.z + (double)ev.w * x1.w;
      s2 += (double)ev.x * x2.x + (double)ev.y * x2.y + (double)ev.z * x2.z + (double)ev.w * x2.w;
      s3 += (double)ev.x * x3.x + (double)ev.y * x3.y + (double)ev.z * x3.z + (double)ev.w * x3.w;
    }
    const double en = enorm_d[c];
    const double dd[4] = {en - 2.0 * s0, en - 2.0 * s1, en - 2.0 * s2, en - 2.0 * s3};
    #pragma unroll
    for (int r = 0; r < 4; ++r)
      if (dd[r] < best[r]) { best[r] = dd[r]; bi[r] = c; }
  }
  for (int r = 0; r < nr; ++r) {
    rv[threadIdx.x] = best[r];
    ri[threadIdx.x] = bi[r];
    __syncthreads();
    for (int off = 128; off > 0; off >>= 1) {
      if (threadIdx.x < off) {
        const double ov = rv[threadIdx.x + off];
        const int oi = ri[threadIdx.x + off];
        if (ov < rv[threadIdx.x] || (ov == rv[threadIdx.x] && oi < ri[threadIdx.x])) {
          rv[threadIdx.x] = ov;
          ri[threadIdx.x] = oi;
        }
      }
      __syncthreads();
    }
    if (threadIdx.x == 0) idx_ws[flag_rows[fbase + r]] = ri[0];
    __syncthreads();
  }
}

// ---- phase 3: gather + indices + fp64 loss ----
__global__ __launch_bounds__(256) void gather_loss(
    const float* __restrict__ X, const float* __restrict__ E,
    const int* __restrict__ idx_ws, float* __restrict__ out,
    double* __restrict__ loss_part) {
  const int t = threadIdx.x;
  const int rsub = t >> 6, c4 = t & 63;
  const int rowBase = blockIdx.x * 16;
  double ls = 0.0;
  #pragma unroll
  for (int i = 0; i < 4; ++i) {
    const int row = rowBase + i * 4 + rsub;
    const int idx = idx_ws[row];
    const float4 q = ((const float4*)E)[(size_t)idx * 64 + c4];
    const float4 x = ((const float4*)X)[(size_t)row * 64 + c4];
    ((float4*)out)[(size_t)row * 64 + c4] = q;
    const double d0 = (double)q.x - (double)x.x;
    const double d1 = (double)q.y - (double)x.y;
    const double d2 = (double)q.z - (double)x.z;
    const double d3 = (double)q.w - (double)x.w;
    ls += d0 * d0 + d1 * d1 + d2 * d2 + d3 * d3;
    if (c4 == 0) out[IDX_OFF + row] = (float)idx;
  }
  for (int o = 32; o > 0; o >>= 1) ls += __shfl_down(ls, o, 64);
  __shared__ double wsum[4];
  if ((t & 63) == 0) wsum[t >> 6] = ls;
  __syncthreads();
  if (t == 0)
    atomicAdd(&loss_part[blockIdx.x & 63], wsum[0] + wsum[1] + wsum[2] + wsum[3]);
}

__global__ __launch_bounds__(64) void finalize(
    const double* __restrict__ loss_part, float* __restrict__ out) {
  double v = loss_part[threadIdx.x];
  for (int o = 32; o > 0; o >>= 1) v += __shfl_down(v, o, 64);
  if (threadIdx.x == 0) out[LOSS_OFF] = (float)(v / 16777216.0);
}

extern "C" void kernel_launch(void* const* d_in, const int* in_sizes, int n_in,
                              void* d_out, int out_size, void* d_ws, size_t ws_size,
                              hipStream_t stream) {
  const float* X = (const float*)d_in[0];  // [65536, 256]
  const float* E = (const float*)d_in[1];  // [1024, 256]
  float* out = (float*)d_out;
  char* ws = (char*)d_ws;

  int*    flag1     = (int*)(ws + WS_FLAG1);
  double* loss_part = (double*)(ws + WS_LOSSP);
  double* enorm_d   = (double*)(ws + WS_ENORMD);
  float*  enorm_f   = (float*)(ws + WS_ENORMF);
  int*    flag_rows = (int*)(ws + WS_FROWS);
  int*    idx_ws    = (int*)(ws + WS_IDX);
  uint4*  Ehi       = (uint4*)(ws + WS_EHI);
  uint4*  Elo       = (uint4*)(ws + WS_ELO);

  hipLaunchKernelGGL(init_kernel, dim3(4), dim3(256), 0, stream,
                     E, enorm_d, enorm_f, Ehi, Elo, flag1, loss_part);
  hipLaunchKernelGGL(dist_argmin_mfma, dim3(NROWS / 64), dim3(256), 0, stream,
                     X, Ehi, Elo, enorm_f, idx_ws, flag1, flag_rows);
  hipLaunchKernelGGL(fixup64, dim3(FLAG_CAP / 4), dim3(256), 0, stream,
                     X, E, enorm_d, flag1, flag_rows, idx_ws);
  hipLaunchKernelGGL(gather_loss, dim3(NROWS / 16), dim3(256), 0, stream,
                     X, E, idx_ws, out, loss_part);
  hipLaunchKernelGGL(finalize, dim3(1), dim3(64), 0, stream, loss_part, out);
}

// Round 4
// 236.799 us; speedup vs baseline: 4.9023x; 1.0958x over previous
//
#include <hip/hip_runtime.h>
#include <float.h>

#define NROWS 65536
#define DK 256
#define NCODES 1024
#define FLAG_CAP 8192
#define MARGIN1 0.15f   // f16 single-pass: sigma_d ~0.0065 -> 23 sigma + granule 0.0156
#define D_BIAS 384.0f   // d = enorm + 384 - 2acc in (394, 894): 8-bit pack granule <= 2^-6

#define LOSS_OFF 16777216
#define IDX_OFF  16777217

// ---------------- ws layout (bytes) ----------------
#define WS_FLAG1   0        // int
#define WS_LOSSP   8        // double[64]
#define WS_ENORMD  520      // double[1024]
#define WS_ENORMF  8712     // float[1024]
#define WS_FROWS   12808    // int[FLAG_CAP] -> ends 45576
#define WS_IDX     45576    // int[65536]    -> ends 307720
#define WS_EHI     307728   // fp16[1024*256] frag-swizzled (512 KB)

typedef _Float16 f16x8 __attribute__((ext_vector_type(8)));
typedef float f32x4 __attribute__((ext_vector_type(4)));
typedef unsigned int uint32;

__device__ __forceinline__ uint32 packh2(float a, float b) {
  return (uint32)__builtin_bit_cast(unsigned short, (_Float16)a) |
         ((uint32)__builtin_bit_cast(unsigned short, (_Float16)b) << 16);
}

// ---- init: counters, fp64 E norms, E -> f16 fragment-swizzled Ehi ----
// 128 blocks x 256 thr: 8 codes/block, 32 threads/code, 8 elements/thread.
__global__ __launch_bounds__(256) void init_kernel(
    const float* __restrict__ E, double* __restrict__ enorm_d,
    float* __restrict__ enorm_f, uint4* __restrict__ Ehi,
    int* __restrict__ flag1, double* __restrict__ loss_part) {
  const int t = threadIdx.x;
  const int c = blockIdx.x * 8 + (t >> 5);
  const int g = t & 31;  // 8-element group within the code row
  if (blockIdx.x == 0) {
    if (t == 0) *flag1 = 0;
    if (t < 64) loss_part[t] = 0.0;
  }
  const float4* er4 = (const float4*)(E + (size_t)c * DK);
  const float4 va = er4[g * 2];
  const float4 vb = er4[g * 2 + 1];
  double s = (double)va.x * va.x + (double)va.y * va.y + (double)va.z * va.z + (double)va.w * va.w
           + (double)vb.x * vb.x + (double)vb.y * vb.y + (double)vb.z * vb.z + (double)vb.w * vb.w;
  uint4 h;
  h.x = packh2(va.x, va.y);
  h.y = packh2(va.z, va.w);
  h.z = packh2(vb.x, vb.y);
  h.w = packh2(vb.z, vb.w);
  const int ctg = c >> 8, cga = (c >> 4) & 15, col = c & 15;
  const int kc = g >> 2, quad = g & 3;
  Ehi[((size_t)((ctg * 8 + kc) * 16 + cga)) * 64 + (size_t)(quad * 16 + col)] = h;
  #pragma unroll
  for (int m = 1; m < 32; m <<= 1) s += __shfl_xor(s, m, 64);
  if (g == 0) {
    enorm_d[c] = s;
    enorm_f[c] = (float)s;
  }
}

// ---- phase 1 (fused): f16 MFMA distances + top-2 argmin + gather/loss tail ----
// 256 thr / 4 waves, 64 rows x all 1024 codes per block. A resident in 32 KB
// LDS (frag order); B fragments global->VGPR from swizzled Ehi (zero reuse in
// block => no LDS hop, barrier-free K loop). Tail: gather E rows (provisional
// idx), write quantized + idx, fp64 loss partials.
__global__ __launch_bounds__(256, 2) void dist_fused(
    const float* __restrict__ X, const uint4* __restrict__ Ehi,
    const float* __restrict__ E, const float* __restrict__ enorm_f,
    int* __restrict__ idx_ws, int* __restrict__ flag1, int* __restrict__ flag_rows,
    float* __restrict__ out, double* __restrict__ loss_part) {
  __shared__ __attribute__((aligned(16))) char lds[32768];
  const int tid = threadIdx.x;
  const int lane = tid & 63;
  const int wid = tid >> 6;
  const int col = lane & 15;
  const int rowBase = blockIdx.x * 64;

  // stage A: 64 rows x 256 k, fp32 -> fp16 RNE, fragment order
  {
    const float4* X4 = (const float4*)X + (size_t)rowBase * 64;
    #pragma unroll
    for (int i = 0; i < 16; ++i) {
      const int f4 = i * 256 + tid;
      const int row = f4 >> 6;
      const int k0 = (f4 & 63) << 2;
      const float4 v = X4[f4];
      uint2 p;
      p.x = packh2(v.x, v.y);
      p.y = packh2(v.z, v.w);
      const int off = (((row >> 4) * 8 + (k0 >> 5)) * 64 + ((k0 >> 3) & 3) * 16 + (row & 15)) * 16
                      + ((k0 >> 2) & 1) * 8;
      *(uint2*)(lds + off) = p;
    }
  }
  __syncthreads();

  float rv1[16], rv2[16];  // packed top-2 per row; wave-local idx in low 8 bits
  #pragma unroll
  for (int i = 0; i < 16; ++i) { rv1[i] = FLT_MAX; rv2[i] = FLT_MAX; }

  for (int ctg = 0; ctg < 4; ++ctg) {
    f32x4 acc[4][4];
    #pragma unroll
    for (int rg = 0; rg < 4; ++rg)
      #pragma unroll
      for (int cg = 0; cg < 4; ++cg) acc[rg][cg] = (f32x4){0.f, 0.f, 0.f, 0.f};

    #pragma unroll 2
    for (int ks = 0; ks < 8; ++ks) {
      const size_t ub = ((size_t)((ctg * 8 + ks) * 16 + wid * 4)) * 64 + (size_t)lane;
      f16x8 a[4], bh[4];
      #pragma unroll
      for (int cg = 0; cg < 4; ++cg) bh[cg] = *(const f16x8*)&Ehi[ub + (size_t)cg * 64];
      #pragma unroll
      for (int rg = 0; rg < 4; ++rg)
        a[rg] = *(const f16x8*)(lds + ((rg * 8 + ks) * 64 + lane) * 16);
      #pragma unroll
      for (int rg = 0; rg < 4; ++rg)
        #pragma unroll
        for (int cg = 0; cg < 4; ++cg)
          acc[rg][cg] = __builtin_amdgcn_mfma_f32_16x16x32_f16(a[rg], bh[cg], acc[rg][cg], 0, 0, 0);
    }
    // epilogue: d = ||e||^2 + BIAS - 2 acc; pack wave-local idx (8 bits)
    #pragma unroll
    for (int cg = 0; cg < 4; ++cg) {
      const int code = ctg * 256 + wid * 64 + cg * 16 + col;
      const float en = enorm_f[code] + D_BIAS;
      const uint32 li = (uint32)((ctg << 6) | (cg << 4) | col);
      #pragma unroll
      for (int rg = 0; rg < 4; ++rg)
        #pragma unroll
        for (int reg = 0; reg < 4; ++reg) {
          const int i = rg * 4 + reg;
          const float d = fmaf(-2.0f, acc[rg][cg][reg], en);
          const float p = __builtin_bit_cast(float,
              (__builtin_bit_cast(uint32, d) & 0xFFFFFF00u) | li);
          rv2[i] = fminf(rv2[i], fmaxf(rv1[i], p));
          rv1[i] = fminf(rv1[i], p);
        }
    }
  }

  // merge 16 cols within each quad (packed => lowest local idx wins ties)
  #pragma unroll
  for (int i = 0; i < 16; ++i) {
    #pragma unroll
    for (int m = 1; m < 16; m <<= 1) {
      const float o1 = __shfl_xor(rv1[i], m, 64);
      const float o2 = __shfl_xor(rv2[i], m, 64);
      rv2[i] = fminf(fminf(rv2[i], o2), fmaxf(rv1[i], o1));
      rv1[i] = fminf(rv1[i], o1);
    }
  }

  __syncthreads();  // all waves done reading A region
  float* M = (float*)lds;          // [row 64][wave 4][2]  (2 KB)
  int* idxs = (int*)(lds + 4096);  // [64]
  if (col == 0) {
    const int quad = lane >> 4;
    #pragma unroll
    for (int i = 0; i < 16; ++i) {
      const int row = (i >> 2) * 16 + quad * 4 + (i & 3);
      M[(row * 4 + wid) * 2 + 0] = rv1[i];
      M[(row * 4 + wid) * 2 + 1] = rv2[i];
    }
  }
  __syncthreads();
  if (tid < 64) {
    const float a1 = M[(tid * 4 + 0) * 2], a2 = M[(tid * 4 + 0) * 2 + 1];
    const float b1 = M[(tid * 4 + 1) * 2], b2 = M[(tid * 4 + 1) * 2 + 1];
    const float c1 = M[(tid * 4 + 2) * 2], c2 = M[(tid * 4 + 2) * 2 + 1];
    const float d1 = M[(tid * 4 + 3) * 2], d2 = M[(tid * 4 + 3) * 2 + 1];
    const float lo1 = fminf(a1, b1), hi1 = fmaxf(a1, b1);
    const float lo2 = fminf(c1, d1), hi2 = fmaxf(c1, d1);
    const float r1 = fminf(lo1, lo2);
    const float s1 = fminf(fmaxf(lo1, lo2), fminf(hi1, hi2));
    const float r2 = fminf(fminf(fminf(a2, b2), fminf(c2, d2)), s1);
    const int w1 = (r1 == a1) ? 0 : (r1 == b1) ? 1 : (r1 == c1) ? 2 : 3;
    const uint32 u1 = __builtin_bit_cast(uint32, r1);
    const int li = (int)(u1 & 255u);
    const int code = ((li >> 6) & 3) * 256 + w1 * 64 + ((li >> 4) & 3) * 16 + (li & 15);
    const int row = rowBase + tid;
    idxs[tid] = code;
    idx_ws[row] = code;
    out[IDX_OFF + row] = (float)code;
    const float q1 = __builtin_bit_cast(float, u1 & 0xFFFFFF00u);
    const float q2 = __builtin_bit_cast(float, __builtin_bit_cast(uint32, r2) & 0xFFFFFF00u);
    if (q2 - q1 < MARGIN1) {
      const int p = atomicAdd(flag1, 1);
      if (p < FLAG_CAP) flag_rows[p] = row;
    }
  }
  __syncthreads();

  // fused tail: gather quantized, write, fp64 loss partial (provisional idx;
  // fixup64 rewrites flagged rows and adjusts the loss by the exact delta)
  const int rsub = tid >> 6, c4 = tid & 63;
  double ls = 0.0;
  #pragma unroll 4
  for (int i = 0; i < 16; ++i) {
    const int rl = i * 4 + rsub;
    const int row = rowBase + rl;
    const int idx = idxs[rl];
    const float4 q = ((const float4*)E)[(size_t)idx * 64 + c4];
    const float4 x = ((const float4*)X)[(size_t)row * 64 + c4];
    ((float4*)out)[(size_t)row * 64 + c4] = q;
    const double d0 = (double)q.x - (double)x.x;
    const double d1 = (double)q.y - (double)x.y;
    const double d2 = (double)q.z - (double)x.z;
    const double d3 = (double)q.w - (double)x.w;
    ls += d0 * d0 + d1 * d1 + d2 * d2 + d3 * d3;
  }
  #pragma unroll
  for (int o = 32; o > 0; o >>= 1) ls += __shfl_down(ls, o, 64);
  __shared__ double wsum[4];
  if ((tid & 63) == 0) wsum[tid >> 6] = ls;
  __syncthreads();
  if (tid == 0)
    atomicAdd(&loss_part[blockIdx.x & 63], wsum[0] + wsum[1] + wsum[2] + wsum[3]);
}

// ---- phase 2: exact fp64 re-resolution of flagged rows (4 rows/block) ----
// Also rewrites quantized output + idx and adjusts loss by (d_new - d_old).
__global__ __launch_bounds__(256) void fixup64(
    const float* __restrict__ X, const float* __restrict__ E,
    const double* __restrict__ enorm_d, const int* __restrict__ flag1,
    const int* __restrict__ flag_rows, const int* __restrict__ idx_ws,
    float* __restrict__ out, double* __restrict__ loss_part) {
  __shared__ float xs[4][256];
  __shared__ double rv[256];
  __shared__ int ri[256];
  __shared__ int rowsh[4], oldsh[4], newsh[4];
  __shared__ double dold_sh[4], dnew_sh[4];
  int cnt = *flag1;
  if (cnt > FLAG_CAP) cnt = FLAG_CAP;
  const int fbase = blockIdx.x * 4;
  if (fbase >= cnt) return;
  const int nr = min(4, cnt - fbase);
  if (threadIdx.x < 4) {
    const int r = threadIdx.x;
    const int row = (r < nr) ? flag_rows[fbase + r] : flag_rows[fbase];
    rowsh[r] = row;
    oldsh[r] = idx_ws[row];
  }
  __syncthreads();
  for (int e = threadIdx.x; e < 4 * 256; e += 256) {
    const int r = e >> 8, k = e & 255;
    xs[r][k] = X[(size_t)rowsh[r] * DK + k];
  }
  __syncthreads();
  double best[4] = {1e300, 1e300, 1e300, 1e300};
  int bi[4] = {0x7fffffff, 0x7fffffff, 0x7fffffff, 0x7fffffff};
  for (int cc = 0; cc < 4; ++cc) {
    const int c = cc * 256 + threadIdx.x;  // ascending per thread => '<' keeps lowest
    const float4* E4 = (const float4*)(E + (size_t)c * DK);
    double s0 = 0.0, s1 = 0.0, s2 = 0.0, s3 = 0.0;
    #pragma unroll 4
    for (int q = 0; q < 64; ++q) {
      const float4 ev = E4[q];
      const float4 x0 = ((const float4*)xs[0])[q];
      const float4 x1 = ((const float4*)xs[1])[q];
      const float4 x2 = ((const float4*)xs[2])[q];
      const float4 x3 = ((const float4*)xs[3])[q];
      s0 += (double)ev.x * x0.x + (double)ev.y * x0.y + (double)ev.z * x0.z + (double)ev.w * x0.w;
      s1 += (double)ev.x * x1.x + (double)ev.y * x1.y + (double)ev.z * x1.z + (double)ev.w * x1.w;
      s2 += (double)ev.x * x2.x + (double)ev.y * x2.y + (double)ev.z * x2.z + (double)ev.w * x2.w;
      s3 += (double)ev.x * x3.x + (double)ev.y * x3.y + (double)ev.z * x3.z + (double)ev.w * x3.w;
    }
    const double en = enorm_d[c];
    const double dd[4] = {en - 2.0 * s0, en - 2.0 * s1, en - 2.0 * s2, en - 2.0 * s3};
    #pragma unroll
    for (int r = 0; r < 4; ++r) {
      if (dd[r] < best[r]) { best[r] = dd[r]; bi[r] = c; }
      if (c == oldsh[r]) dold_sh[r] = dd[r];  // exactly one thread matches
    }
  }
  for (int r = 0; r < nr; ++r) {
    rv[threadIdx.x] = best[r];
    ri[threadIdx.x] = bi[r];
    __syncthreads();
    for (int off = 128; off > 0; off >>= 1) {
      if (threadIdx.x < off) {
        const double ov = rv[threadIdx.x + off];
        const int oi = ri[threadIdx.x + off];
        if (ov < rv[threadIdx.x] || (ov == rv[threadIdx.x] && oi < ri[threadIdx.x])) {
          rv[threadIdx.x] = ov;
          ri[threadIdx.x] = oi;
        }
      }
      __syncthreads();
    }
    if (threadIdx.x == 0) { dnew_sh[r] = rv[0]; newsh[r] = ri[0]; }
    __syncthreads();
  }
  // rewrite corrected rows + adjust loss
  for (int r = 0; r < nr; ++r) {
    const int newi = newsh[r];
    if (newi != oldsh[r]) {
      const int row = rowsh[r];
      out[(size_t)row * DK + threadIdx.x] = E[(size_t)newi * DK + threadIdx.x];
      if (threadIdx.x == 0) {
        out[IDX_OFF + row] = (float)newi;
        atomicAdd(&loss_part[row & 63], dnew_sh[r] - dold_sh[r]);
      }
    }
  }
}

__global__ __launch_bounds__(64) void finalize(
    const double* __restrict__ loss_part, float* __restrict__ out) {
  double v = loss_part[threadIdx.x];
  for (int o = 32; o > 0; o >>= 1) v += __shfl_down(v, o, 64);
  if (threadIdx.x == 0) out[LOSS_OFF] = (float)(v / 16777216.0);
}

extern "C" void kernel_launch(void* const* d_in, const int* in_sizes, int n_in,
                              void* d_out, int out_size, void* d_ws, size_t ws_size,
                              hipStream_t stream) {
  const float* X = (const float*)d_in[0];  // [65536, 256]
  const float* E = (const float*)d_in[1];  // [1024, 256]
  float* out = (float*)d_out;
  char* ws = (char*)d_ws;

  int*    flag1     = (int*)(ws + WS_FLAG1);
  double* loss_part = (double*)(ws + WS_LOSSP);
  double* enorm_d   = (double*)(ws + WS_ENORMD);
  float*  enorm_f   = (float*)(ws + WS_ENORMF);
  int*    flag_rows = (int*)(ws + WS_FROWS);
  int*    idx_ws    = (int*)(ws + WS_IDX);
  uint4*  Ehi       = (uint4*)(ws + WS_EHI);

  hipLaunchKernelGGL(init_kernel, dim3(128), dim3(256), 0, stream,
                     E, enorm_d, enorm_f, Ehi, flag1, loss_part);
  hipLaunchKernelGGL(dist_fused, dim3(NROWS / 64), dim3(256), 0, stream,
                     X, Ehi, E, enorm_f, idx_ws, flag1, flag_rows, out, loss_part);
  hipLaunchKernelGGL(fixup64, dim3(FLAG_CAP / 4), dim3(256), 0, stream,
                     X, E, enorm_d, flag1, flag_rows, idx_ws, out, loss_part);
  hipLaunchKernelGGL(finalize, dim3(1), dim3(64), 0, stream, loss_part, out);
}